// Round 2
// baseline (265.583 us; speedup 1.0000x reference)
//
#include <hip/hip_runtime.h>

// CLIPAttention (ShareKey branch, layer>=9): softmax(scores+bias) == softmax(bias)
// => q/q_w/q_b/share_key are dead. Pipeline (all intermediates fp16, fp32 accum):
//   prep: hs->f16 [16][584][1024] (s-padded, zero rows), v_w/out_w -> f16
//   softmax: P[h][i][j] = softmax_j(share_bias[h,i,:]) -> f16 [16][640][608] zero-padded
//   GEMM1 (transposed): C'[e][b*584+s] = sum_k vw[e,k]*hs[b,s,k] + v_b[e]  (f16)
//   PV: out_h[b*577+i][h*64+d] = sum_j P[h,i,j] * C'[h*64+d][b*584+j]      (f16)
//   GEMM4: out[m][e] = sum_k out_h[m,k]*out_w[e,k] + out_b[e]              (fp32)

typedef __attribute__((ext_vector_type(4))) float f32x4;
typedef __attribute__((ext_vector_type(4))) unsigned int u32x4;

__device__ __forceinline__ unsigned short f2h(float f) {
  union { _Float16 h; unsigned short u; } x;
  x.h = (_Float16)f;   // v_cvt_f16_f32, RNE
  return x.u;
}

__device__ __forceinline__ void mfma16(f32x4& d, u32x4 a, u32x4 b) {
  // v_mfma_f32_16x16x32_f16: D = A*B + C ; A/B = 8 fp16 (4 VGPR), C/D = f32x4
  asm("v_mfma_f32_16x16x32_f16 %0, %1, %2, %0" : "+v"(d) : "v"(a), "v"(b));
}

// ---------------- prep ----------------
__global__ __launch_bounds__(256) void prep_hs_kernel(const float* __restrict__ X,
                                                      unsigned short* __restrict__ Y) {
  int idx = blockIdx.x * 256 + threadIdx.x;   // one thread per 4 elems; grid covers 9344*1024/4
  int n = idx << 2;
  int row = n >> 10;                          // 0..9343  (= b*584 + s)
  int col = n & 1023;
  int b = row / 584;
  int s = row - b * 584;
  unsigned short o0 = 0, o1 = 0, o2 = 0, o3 = 0;
  if (s < 577) {
    const float4 v = *(const float4*)(X + (((size_t)(b * 577 + s)) << 10) + col);
    o0 = f2h(v.x); o1 = f2h(v.y); o2 = f2h(v.z); o3 = f2h(v.w);
  }
  ushort4 o; o.x = o0; o.y = o1; o.z = o2; o.w = o3;
  *(ushort4*)(Y + n) = o;
}

__global__ __launch_bounds__(256) void prep_w_kernel(const float* __restrict__ X,
                                                     unsigned short* __restrict__ Y) {
  int idx = blockIdx.x * 256 + threadIdx.x;   // 1M/4/256 = 1024 blocks
  int n = idx << 2;
  const float4 v = *(const float4*)(X + n);
  ushort4 o; o.x = f2h(v.x); o.y = f2h(v.y); o.z = f2h(v.z); o.w = f2h(v.w);
  *(ushort4*)(Y + n) = o;
}

// ---------------- softmax over share_bias rows ----------------
__global__ __launch_bounds__(256) void softmax_kernel(const float* __restrict__ SB,
                                                      unsigned short* __restrict__ P) {
  const int i = blockIdx.x;   // 0..639
  const int h = blockIdx.y;   // 0..15
  unsigned short* prow = P + ((size_t)h * 640 + i) * 608;
  const int tid = threadIdx.x;
  if (i >= 577) {
    for (int j = tid; j < 608; j += 256) prow[j] = 0;
    return;
  }
  const float* row = SB + ((size_t)h * 577 + i) * 577;
  __shared__ float buf[577];
  __shared__ float redm[4];
  __shared__ float reds[4];
  float lmax = -3.0e38f;
  for (int j = tid; j < 577; j += 256) { float v = row[j]; buf[j] = v; lmax = fmaxf(lmax, v); }
  #pragma unroll
  for (int off = 32; off > 0; off >>= 1) lmax = fmaxf(lmax, __shfl_xor(lmax, off));
  if ((tid & 63) == 0) redm[tid >> 6] = lmax;
  __syncthreads();
  const float m = fmaxf(fmaxf(redm[0], redm[1]), fmaxf(redm[2], redm[3]));
  float lsum = 0.f;
  for (int j = tid; j < 577; j += 256) { float e = __expf(buf[j] - m); buf[j] = e; lsum += e; }
  #pragma unroll
  for (int off = 32; off > 0; off >>= 1) lsum += __shfl_xor(lsum, off);
  if ((tid & 63) == 0) reds[tid >> 6] = lsum;
  __syncthreads();
  const float inv = 1.f / (reds[0] + reds[1] + reds[2] + reds[3]);
  for (int j = tid; j < 608; j += 256)
    prow[j] = (j < 577) ? f2h(buf[j] * inv) : (unsigned short)0;
}

// ---------------- 128x128 BT-GEMM: C[m,n] = sum_k A[m,k]*B[n,k] + bias ----------------
template<int BIASROW, int OUTF32, int CHECKM>
__global__ __launch_bounds__(256) void gemm128_kernel(
    const unsigned short* __restrict__ A, int lda,
    const unsigned short* __restrict__ B, int ldb,
    const float* __restrict__ bias,
    void* __restrict__ Cv, int ldc, int Mstore, int K)
{
  __shared__ unsigned short As[128 * 40];   // +8 pad: 2-way bank alias only
  __shared__ unsigned short Bs[128 * 40];
  const int tid  = threadIdx.x;
  const int lane = tid & 63;
  const int w    = tid >> 6;
  const int wm = w >> 1, wn = w & 1;
  const int m0 = blockIdx.x * 128, n0 = blockIdx.y * 128;
  const int srow = tid >> 2;
  const int scol = (tid & 3) << 3;
  const int l15 = lane & 15;
  const int lhi = lane >> 4;

  const unsigned short* Ap0 = A + (size_t)(m0 + srow) * lda + scol;
  const unsigned short* Ap1 = Ap0 + (size_t)64 * lda;
  const unsigned short* Bp0 = B + (size_t)(n0 + srow) * ldb + scol;
  const unsigned short* Bp1 = Bp0 + (size_t)64 * ldb;

  f32x4 acc[4][4] = {};

  for (int k0 = 0; k0 < K; k0 += 32) {
    u32x4 a0 = *(const u32x4*)(Ap0 + k0);
    u32x4 a1 = *(const u32x4*)(Ap1 + k0);
    u32x4 b0 = *(const u32x4*)(Bp0 + k0);
    u32x4 b1 = *(const u32x4*)(Bp1 + k0);
    __syncthreads();
    *(u32x4*)&As[srow * 40 + scol]        = a0;
    *(u32x4*)&As[(64 + srow) * 40 + scol] = a1;
    *(u32x4*)&Bs[srow * 40 + scol]        = b0;
    *(u32x4*)&Bs[(64 + srow) * 40 + scol] = b1;
    __syncthreads();
    u32x4 af[4], bv[4];
    #pragma unroll
    for (int i = 0; i < 4; i++)
      af[i] = *(const u32x4*)&As[(wm * 64 + i * 16 + l15) * 40 + (lhi << 3)];
    #pragma unroll
    for (int i = 0; i < 4; i++)
      bv[i] = *(const u32x4*)&Bs[(wn * 64 + i * 16 + l15) * 40 + (lhi << 3)];
    #pragma unroll
    for (int i = 0; i < 4; i++)
      #pragma unroll
      for (int j = 0; j < 4; j++)
        mfma16(acc[i][j], af[i], bv[j]);
  }

  const int rb = m0 + wm * 64 + (lhi << 2);
  const int cb = n0 + wn * 64 + l15;
  #pragma unroll
  for (int i = 0; i < 4; i++) {
    #pragma unroll
    for (int r = 0; r < 4; r++) {
      const int row = rb + i * 16 + r;
      if (CHECKM && row >= Mstore) continue;
      const float rbias = BIASROW ? bias[row] : 0.f;
      #pragma unroll
      for (int j = 0; j < 4; j++) {
        const int col = cb + j * 16;
        const float v = acc[i][j][r] + (BIASROW ? rbias : bias[col]);
        if (OUTF32) ((float*)Cv)[(size_t)row * ldc + col] = v;
        else        ((unsigned short*)Cv)[(size_t)row * ldc + col] = f2h(v);
      }
    }
  }
}

// ---------------- batched PV: per (b,h): C[i,d] = sum_j P[h,i,j] * VT[h*64+d, b*584+j] ----------------
__global__ __launch_bounds__(256) void gemm_pv_kernel(
    const unsigned short* __restrict__ P,    // [16][640][608]
    const unsigned short* __restrict__ VT,   // [1024][9344]  (= C' from GEMM1)
    unsigned short* __restrict__ Oh)         // [9344][1024], rows b*577+i
{
  __shared__ unsigned short As[64 * 40];
  __shared__ unsigned short Bs[64 * 40];
  const int tid  = threadIdx.x;
  const int lane = tid & 63;
  const int w    = tid >> 6;
  const int wm = w >> 1, wn = w & 1;
  const int mt = blockIdx.x;          // 0..9 (64-row tiles of padded 640)
  const int g  = blockIdx.y;          // 0..255
  const int b = g >> 4, h = g & 15;
  const int l15 = lane & 15, lhi = lane >> 4;
  const int srow = tid >> 2, scol = (tid & 3) << 3;

  const unsigned short* Ap = P  + ((size_t)h * 640 + mt * 64 + srow) * 608 + scol;
  const unsigned short* Bp = VT + ((size_t)(h * 64 + srow)) * 9344 + b * 584 + scol;

  f32x4 acc[2][2] = {};

  for (int k0 = 0; k0 < 608; k0 += 32) {
    u32x4 a  = *(const u32x4*)(Ap + k0);
    u32x4 bv = *(const u32x4*)(Bp + k0);
    __syncthreads();
    *(u32x4*)&As[srow * 40 + scol] = a;
    *(u32x4*)&Bs[srow * 40 + scol] = bv;
    __syncthreads();
    u32x4 af[2], bf2[2];
    #pragma unroll
    for (int i = 0; i < 2; i++) {
      af[i]  = *(const u32x4*)&As[(wm * 32 + i * 16 + l15) * 40 + (lhi << 3)];
      bf2[i] = *(const u32x4*)&Bs[(wn * 32 + i * 16 + l15) * 40 + (lhi << 3)];
    }
    #pragma unroll
    for (int i = 0; i < 2; i++)
      #pragma unroll
      for (int j = 0; j < 2; j++)
        mfma16(acc[i][j], af[i], bf2[j]);
  }

  const int ib = mt * 64 + wm * 32 + (lhi << 2);
  const int cb = wn * 32 + l15;
  #pragma unroll
  for (int i = 0; i < 2; i++) {
    #pragma unroll
    for (int r = 0; r < 4; r++) {
      const int ii = ib + i * 16 + r;
      if (ii < 577) {
        unsigned short* op = Oh + (((size_t)b * 577 + ii) << 10) + h * 64 + cb;
        #pragma unroll
        for (int j = 0; j < 2; j++) op[j * 16] = f2h(acc[i][j][r]);
      }
    }
  }
}

extern "C" void kernel_launch(void* const* d_in, const int* in_sizes, int n_in,
                              void* d_out, int out_size, void* d_ws, size_t ws_size,
                              hipStream_t stream) {
  (void)in_sizes; (void)n_in; (void)out_size; (void)ws_size;
  const float* hs    = (const float*)d_in[0];
  const float* v_w   = (const float*)d_in[3];
  const float* v_b   = (const float*)d_in[4];
  const float* out_w = (const float*)d_in[5];
  const float* out_b = (const float*)d_in[6];
  const float* sb    = (const float*)d_in[8];
  float* out = (float*)d_out;

  char* ws = (char*)d_ws;
  constexpr size_t HS_SZ = (size_t)9344 * 1024 * 2;        // f16 hs, [16][584][1024]; later reused as out_h
  constexpr size_t W_SZ  = (size_t)1024 * 1024 * 2;
  constexpr size_t VT_SZ = (size_t)1024 * 9344 * 2 + 256;  // + slack for b=15 K-tail reads
  unsigned short* hs_bf = (unsigned short*)(ws);
  unsigned short* vw_bf = (unsigned short*)(ws + HS_SZ);
  unsigned short* ow_bf = (unsigned short*)(ws + HS_SZ + W_SZ);
  unsigned short* vt    = (unsigned short*)(ws + HS_SZ + 2 * W_SZ);
  unsigned short* pmat  = (unsigned short*)(ws + HS_SZ + 2 * W_SZ + VT_SZ);
  // total ws use ~55 MB

  prep_hs_kernel<<<9344, 256, 0, stream>>>(hs, hs_bf);
  prep_w_kernel<<<1024, 256, 0, stream>>>(v_w, vw_bf);
  prep_w_kernel<<<1024, 256, 0, stream>>>(out_w, ow_bf);
  softmax_kernel<<<dim3(640, 16), 256, 0, stream>>>(sb, pmat);
  // GEMM1 transposed: C'[e][n] = sum_k vw[e,k]*hs_bf[n,k] + v_b[e]; M=1024, N=9344, K=1024
  gemm128_kernel<1, 0, 0><<<dim3(8, 73), 256, 0, stream>>>(vw_bf, 1024, hs_bf, 1024, v_b,
                                                           (void*)vt, 9344, 0, 1024);
  // PV: out_h (reuses hs_bf buffer; pad rows >=9232 are stale-but-unused by masked stores)
  gemm_pv_kernel<<<dim3(10, 256), 256, 0, stream>>>(pmat, vt, hs_bf);
  // GEMM4: out[m][e] = sum_k out_h[m,k]*ow[e,k] + out_b[e]; M=9344(store<9232), N=1024, K=1024
  gemm128_kernel<0, 1, 1><<<dim3(73, 8), 256, 0, stream>>>(hs_bf, 1024, ow_bf, 1024, out_b,
                                                           (void*)out, 1024, 9232, 1024);
}

// Round 3
// 250.603 us; speedup vs baseline: 1.0598x; 1.0598x over previous
//
#include <hip/hip_runtime.h>

// CLIPAttention (ShareKey, layer>=9): softmax(scores+bias)==softmax(bias) => q path dead.
// Pipeline (fp16 intermediates, fp32 accum):
//   prep: hs->f16 [16][584][1024]; v_w/out_w->f16
//   softmax: P[h][i][j] -> f16 [16][640][608], zero-padded rows/cols
//   GEMM1 (MODE0): VT[e][b*584+s] = sum_k vw[e,k]*hs[b,s,k] + v_b[e]          (f16)
//   PV    (MODE1): per head h: C[i][n=(b,d)] = sum_j P[h,i,j]*VT[h*64+d][b*584+j] -> out_h
//   GEMM4 (MODE2): out[m][e] = sum_k out_h[m,k]*ow[e,k] + out_b[e]            (f32)
// All GEMMs: 128x128 tile, BK=32, global_load_lds width-16 staging, linear LDS [128][32].

typedef __attribute__((ext_vector_type(4))) float f32x4;
typedef __attribute__((ext_vector_type(4))) unsigned int u32x4;

__device__ __forceinline__ unsigned short f2h(float f) {
  union { _Float16 h; unsigned short u; } x;
  x.h = (_Float16)f;
  return x.u;
}

__device__ __forceinline__ void mfma16(f32x4& d, u32x4 a, u32x4 b) {
  asm("v_mfma_f32_16x16x32_f16 %0, %1, %2, %0" : "+v"(d) : "v"(a), "v"(b));
}

__device__ __forceinline__ void gl_lds16(const unsigned short* g, unsigned short* l) {
  __builtin_amdgcn_global_load_lds(
      (const __attribute__((address_space(1))) unsigned int*)g,
      (__attribute__((address_space(3))) unsigned int*)l, 16, 0, 0);
}

// ---------------- prep ----------------
__global__ __launch_bounds__(256) void prep_hs_kernel(const float* __restrict__ X,
                                                      unsigned short* __restrict__ Y) {
  int idx = blockIdx.x * 256 + threadIdx.x;
  int n = idx << 2;
  int row = n >> 10;                          // 0..9343  (= b*584 + s)
  int col = n & 1023;
  int b = row / 584;
  int s = row - b * 584;
  unsigned short o0 = 0, o1 = 0, o2 = 0, o3 = 0;
  if (s < 577) {
    const float4 v = *(const float4*)(X + (((size_t)(b * 577 + s)) << 10) + col);
    o0 = f2h(v.x); o1 = f2h(v.y); o2 = f2h(v.z); o3 = f2h(v.w);
  }
  ushort4 o; o.x = o0; o.y = o1; o.z = o2; o.w = o3;
  *(ushort4*)(Y + n) = o;
}

__global__ __launch_bounds__(256) void prep_w_kernel(const float* __restrict__ X,
                                                     unsigned short* __restrict__ Y) {
  int idx = blockIdx.x * 256 + threadIdx.x;
  int n = idx << 2;
  const float4 v = *(const float4*)(X + n);
  ushort4 o; o.x = f2h(v.x); o.y = f2h(v.y); o.z = f2h(v.z); o.w = f2h(v.w);
  *(ushort4*)(Y + n) = o;
}

// ---------------- softmax over share_bias rows ----------------
__global__ __launch_bounds__(256) void softmax_kernel(const float* __restrict__ SB,
                                                      unsigned short* __restrict__ P) {
  const int i = blockIdx.x;   // 0..639
  const int h = blockIdx.y;   // 0..15
  unsigned short* prow = P + ((size_t)h * 640 + i) * 608;
  const int tid = threadIdx.x;
  if (i >= 577) {
    for (int j = tid; j < 608; j += 256) prow[j] = 0;
    return;
  }
  const float* row = SB + ((size_t)h * 577 + i) * 577;
  __shared__ float buf[577];
  __shared__ float redm[4];
  __shared__ float reds[4];
  float lmax = -3.0e38f;
  for (int j = tid; j < 577; j += 256) { float v = row[j]; buf[j] = v; lmax = fmaxf(lmax, v); }
  #pragma unroll
  for (int off = 32; off > 0; off >>= 1) lmax = fmaxf(lmax, __shfl_xor(lmax, off));
  if ((tid & 63) == 0) redm[tid >> 6] = lmax;
  __syncthreads();
  const float m = fmaxf(fmaxf(redm[0], redm[1]), fmaxf(redm[2], redm[3]));
  float lsum = 0.f;
  for (int j = tid; j < 577; j += 256) { float e = __expf(buf[j] - m); buf[j] = e; lsum += e; }
  #pragma unroll
  for (int off = 32; off > 0; off >>= 1) lsum += __shfl_xor(lsum, off);
  if ((tid & 63) == 0) reds[tid >> 6] = lsum;
  __syncthreads();
  const float inv = 1.f / (reds[0] + reds[1] + reds[2] + reds[3]);
  for (int j = tid; j < 608; j += 256)
    prow[j] = (j < 577) ? f2h(buf[j] * inv) : (unsigned short)0;
}

// ---------------- unified 128x128 BT-GEMM with global_load_lds staging ----------------
// C[m,n] = sum_k A[m,k] * B[n,k] (+bias). MODE: 0=GEMM1, 1=PV, 2=GEMM4.
template<int MODE>
__global__ __launch_bounds__(256) void gemm_glds_kernel(
    const unsigned short* __restrict__ A, int lda,
    const unsigned short* __restrict__ B, int ldb,
    const float* __restrict__ bias,
    void* __restrict__ Cv, int ldc, int K)
{
  __shared__ unsigned short As[128 * 32];
  __shared__ unsigned short Bs[128 * 32];
  const int tid  = threadIdx.x;
  const int lane = tid & 63;
  const int w    = tid >> 6;
  const int wm = w >> 1, wn = w & 1;
  const int m0 = blockIdx.x * 128, n0 = blockIdx.y * 128;
  const int hh = (MODE == 1) ? blockIdx.z : 0;
  const int l15 = lane & 15;
  const int lhi = lane >> 4;

  // staging geometry: per wave-call, 16 rows x 32 cols (1 KB); lane -> (row=l>>2, col=(l&3)*8)
  const int lr = lane >> 2;
  const int lc = (lane & 3) << 3;

  if (MODE == 1) A += (size_t)hh * 640 * 608;

  const unsigned short* gA0 = A + (size_t)(m0 + w * 32 + lr) * lda + lc;
  const unsigned short* gA1 = gA0 + (size_t)16 * lda;

  const unsigned short* gB0;
  const unsigned short* gB1;
  if (MODE == 1) {
    // B row n -> VT[hh*64 + (n&63)] at column offset (n>>6)*584
    const int nb0 = n0 + w * 32 + lr;
    const int nb1 = nb0 + 16;
    gB0 = B + (size_t)(hh * 64 + (nb0 & 63)) * 9344 + (nb0 >> 6) * 584 + lc;
    gB1 = B + (size_t)(hh * 64 + (nb1 & 63)) * 9344 + (nb1 >> 6) * 584 + lc;
  } else {
    gB0 = B + (size_t)(n0 + w * 32 + lr) * ldb + lc;
    gB1 = gB0 + (size_t)16 * ldb;
  }

  unsigned short* lA0 = As + (w * 32) * 32;        // wave-uniform; lane adds lane*16B
  unsigned short* lA1 = As + (w * 32 + 16) * 32;
  unsigned short* lB0 = Bs + (w * 32) * 32;
  unsigned short* lB1 = Bs + (w * 32 + 16) * 32;

  f32x4 acc[4][4] = {};

  for (int k0 = 0; k0 < K; k0 += 32) {
    gl_lds16(gA0 + k0, lA0);
    gl_lds16(gA1 + k0, lA1);
    gl_lds16(gB0 + k0, lB0);
    gl_lds16(gB1 + k0, lB1);
    __syncthreads();   // compiler drains vmcnt before barrier -> LDS tile ready
    u32x4 af[4], bv[4];
    #pragma unroll
    for (int i = 0; i < 4; i++)
      af[i] = *(const u32x4*)&As[(wm * 64 + i * 16 + l15) * 32 + (lhi << 3)];
    #pragma unroll
    for (int i = 0; i < 4; i++)
      bv[i] = *(const u32x4*)&Bs[(wn * 64 + i * 16 + l15) * 32 + (lhi << 3)];
    #pragma unroll
    for (int i = 0; i < 4; i++)
      #pragma unroll
      for (int j = 0; j < 4; j++)
        mfma16(acc[i][j], af[i], bv[j]);
    __syncthreads();   // all waves done reading before next stage overwrites
  }

  const int rb = m0 + wm * 64 + (lhi << 2);
  const int cb = n0 + wn * 64 + l15;
  #pragma unroll
  for (int i = 0; i < 4; i++) {
    #pragma unroll
    for (int r = 0; r < 4; r++) {
      const int row = rb + i * 16 + r;
      if (MODE == 0) {
        const float rbias = bias[row];
        #pragma unroll
        for (int j = 0; j < 4; j++) {
          const int col = cb + j * 16;
          ((unsigned short*)Cv)[(size_t)row * ldc + col] = f2h(acc[i][j][r] + rbias);
        }
      } else if (MODE == 1) {
        if (row < 577) {
          #pragma unroll
          for (int j = 0; j < 4; j++) {
            const int n = cb + j * 16;
            const int b = n >> 6, d = n & 63;
            ((unsigned short*)Cv)[(((size_t)b * 577 + row) << 10) + hh * 64 + d] =
                f2h(acc[i][j][r]);
          }
        }
      } else {
        if (row < 9232) {
          #pragma unroll
          for (int j = 0; j < 4; j++) {
            const int col = cb + j * 16;
            ((float*)Cv)[(size_t)row * ldc + col] = acc[i][j][r] + bias[col];
          }
        }
      }
    }
  }
}

extern "C" void kernel_launch(void* const* d_in, const int* in_sizes, int n_in,
                              void* d_out, int out_size, void* d_ws, size_t ws_size,
                              hipStream_t stream) {
  (void)in_sizes; (void)n_in; (void)out_size; (void)ws_size;
  const float* hs    = (const float*)d_in[0];
  const float* v_w   = (const float*)d_in[3];
  const float* v_b   = (const float*)d_in[4];
  const float* out_w = (const float*)d_in[5];
  const float* out_b = (const float*)d_in[6];
  const float* sb    = (const float*)d_in[8];
  float* out = (float*)d_out;

  char* ws = (char*)d_ws;
  constexpr size_t HS_SZ = (size_t)9344 * 1024 * 2;        // f16 hs; later reused as out_h
  constexpr size_t W_SZ  = (size_t)1024 * 1024 * 2;
  constexpr size_t VT_SZ = (size_t)1024 * 9344 * 2 + 256;  // + slack for b=15 K-tail reads
  unsigned short* hs_f16 = (unsigned short*)(ws);
  unsigned short* vw_f16 = (unsigned short*)(ws + HS_SZ);
  unsigned short* ow_f16 = (unsigned short*)(ws + HS_SZ + W_SZ);
  unsigned short* vt     = (unsigned short*)(ws + HS_SZ + 2 * W_SZ);
  unsigned short* pmat   = (unsigned short*)(ws + HS_SZ + 2 * W_SZ + VT_SZ);

  prep_hs_kernel<<<9344, 256, 0, stream>>>(hs, hs_f16);
  prep_w_kernel<<<1024, 256, 0, stream>>>(v_w, vw_f16);
  prep_w_kernel<<<1024, 256, 0, stream>>>(out_w, ow_f16);
  softmax_kernel<<<dim3(640, 16), 256, 0, stream>>>(sb, pmat);
  // GEMM1: VT[e][nn] = vw[e,:]·hs[nn,:] + v_b[e]; M=1024, N=9344, K=1024
  gemm_glds_kernel<0><<<dim3(8, 73), 256, 0, stream>>>(vw_f16, 1024, hs_f16, 1024, v_b,
                                                       (void*)vt, 9344, 1024);
  // PV per head: M=640(P rows), N=1024(=(b,d)), K=608; writes out_h into hs_f16 buffer
  gemm_glds_kernel<1><<<dim3(5, 8, 16), 256, 0, stream>>>(pmat, 608, vt, 0, nullptr,
                                                          (void*)hs_f16, 0, 608);
  // GEMM4: out[m][e] = out_h[m,:]·ow[e,:] + out_b[e]; M=9344(store<9232), N=1024, K=1024
  gemm_glds_kernel<2><<<dim3(73, 8), 256, 0, stream>>>(hs_f16, 1024, ow_f16, 1024, out_b,
                                                       (void*)out, 1024, 1024);
}

// Round 4
// 213.631 us; speedup vs baseline: 1.2432x; 1.1731x over previous
//
#include <hip/hip_runtime.h>

// CLIPAttention (ShareKey, layer>=9): softmax(scores+bias)==softmax(bias) => q path dead.
// Pipeline (fp16 intermediates, fp32 accum):
//   prep: hs->f16 [16][584][1024]; v_w/out_w->f16
//   softmax: P[h][i][j] -> f16 [16][640][608], zero-padded rows/cols
//   GEMM1 (MODE0): VT[e][b*584+s] = sum_k vw[e,k]*hs[b,s,k] + v_b[e]          (f16)
//   PV    (MODE1): per head h: C[i][n=(b,d)] = sum_j P[h,i,j]*VT[h*64+d][b*584+j] -> out_h
//   GEMM4 (MODE2): out[m][e] = sum_k out_h[m,k]*ow[e,k] + out_b[e]            (f32)
// GEMMs: 128x128 tile, BK=32, global_load_lds(16B) staging, DOUBLE-buffered LDS
// (separate arrays, 1 barrier/K-step, stage-ahead), bijective XCD-chunk swizzle.

typedef __attribute__((ext_vector_type(4))) float f32x4;
typedef __attribute__((ext_vector_type(4))) unsigned int u32x4;

__device__ __forceinline__ unsigned short f2h(float f) {
  union { _Float16 h; unsigned short u; } x;
  x.h = (_Float16)f;
  return x.u;
}

__device__ __forceinline__ void mfma16(f32x4& d, u32x4 a, u32x4 b) {
  asm("v_mfma_f32_16x16x32_f16 %0, %1, %2, %0" : "+v"(d) : "v"(a), "v"(b));
}

__device__ __forceinline__ void gl_lds16(const unsigned short* g, unsigned short* l) {
  __builtin_amdgcn_global_load_lds(
      (const __attribute__((address_space(1))) unsigned int*)g,
      (__attribute__((address_space(3))) unsigned int*)l, 16, 0, 0);
}

// ---------------- prep ----------------
__global__ __launch_bounds__(256) void prep_hs_kernel(const float* __restrict__ X,
                                                      unsigned short* __restrict__ Y) {
  int idx = blockIdx.x * 256 + threadIdx.x;
  int n = idx << 2;
  int row = n >> 10;                          // 0..9343  (= b*584 + s)
  int col = n & 1023;
  int b = row / 584;
  int s = row - b * 584;
  unsigned short o0 = 0, o1 = 0, o2 = 0, o3 = 0;
  if (s < 577) {
    const float4 v = *(const float4*)(X + (((size_t)(b * 577 + s)) << 10) + col);
    o0 = f2h(v.x); o1 = f2h(v.y); o2 = f2h(v.z); o3 = f2h(v.w);
  }
  ushort4 o; o.x = o0; o.y = o1; o.z = o2; o.w = o3;
  *(ushort4*)(Y + n) = o;
}

__global__ __launch_bounds__(256) void prep_w_kernel(const float* __restrict__ X,
                                                     unsigned short* __restrict__ Y) {
  int idx = blockIdx.x * 256 + threadIdx.x;
  int n = idx << 2;
  const float4 v = *(const float4*)(X + n);
  ushort4 o; o.x = f2h(v.x); o.y = f2h(v.y); o.z = f2h(v.z); o.w = f2h(v.w);
  *(ushort4*)(Y + n) = o;
}

// ---------------- softmax over share_bias rows ----------------
__global__ __launch_bounds__(256) void softmax_kernel(const float* __restrict__ SB,
                                                      unsigned short* __restrict__ P) {
  const int i = blockIdx.x;   // 0..639
  const int h = blockIdx.y;   // 0..15
  unsigned short* prow = P + ((size_t)h * 640 + i) * 608;
  const int tid = threadIdx.x;
  if (i >= 577) {
    for (int j = tid; j < 608; j += 256) prow[j] = 0;
    return;
  }
  const float* row = SB + ((size_t)h * 577 + i) * 577;
  __shared__ float buf[577];
  __shared__ float redm[4];
  __shared__ float reds[4];
  float lmax = -3.0e38f;
  for (int j = tid; j < 577; j += 256) { float v = row[j]; buf[j] = v; lmax = fmaxf(lmax, v); }
  #pragma unroll
  for (int off = 32; off > 0; off >>= 1) lmax = fmaxf(lmax, __shfl_xor(lmax, off));
  if ((tid & 63) == 0) redm[tid >> 6] = lmax;
  __syncthreads();
  const float m = fmaxf(fmaxf(redm[0], redm[1]), fmaxf(redm[2], redm[3]));
  float lsum = 0.f;
  for (int j = tid; j < 577; j += 256) { float e = __expf(buf[j] - m); buf[j] = e; lsum += e; }
  #pragma unroll
  for (int off = 32; off > 0; off >>= 1) lsum += __shfl_xor(lsum, off);
  if ((tid & 63) == 0) reds[tid >> 6] = lsum;
  __syncthreads();
  const float inv = 1.f / (reds[0] + reds[1] + reds[2] + reds[3]);
  for (int j = tid; j < 608; j += 256)
    prow[j] = (j < 577) ? f2h(buf[j] * inv) : (unsigned short)0;
}

// ---------------- unified 128x128 BT-GEMM, dbuf LDS, XCD swizzle ----------------
// C[m,n] = sum_k A[m,k] * B[n,k] (+bias). MODE: 0=GEMM1, 1=PV, 2=GEMM4. 1D grid.
template<int MODE>
__global__ __launch_bounds__(256) void gemm_db_kernel(
    const unsigned short* __restrict__ A, int lda,
    const unsigned short* __restrict__ B, int ldb,
    const float* __restrict__ bias,
    void* __restrict__ Cv, int ldc, int K)
{
  __shared__ unsigned short As0[128 * 32];
  __shared__ unsigned short Bs0[128 * 32];
  __shared__ unsigned short As1[128 * 32];
  __shared__ unsigned short Bs1[128 * 32];
  const int tid  = threadIdx.x;
  const int lane = tid & 63;
  const int w    = tid >> 6;
  const int wm = w >> 1, wn = w & 1;
  const int l15 = lane & 15, lhi = lane >> 4;
  const int lr = lane >> 2, lc = (lane & 3) << 3;

  // bijective XCD-chunk swizzle (gridDim.x % 8 == 0): blocks orig%8==x sit on XCD x
  // and receive a contiguous logical-id chunk -> tile-sharing stays within one L2.
  const int nwg8 = (int)gridDim.x >> 3;
  const int orig = blockIdx.x;
  const int id = (orig & 7) * nwg8 + (orig >> 3);
  int mt, nt, hh = 0;
  if (MODE == 1)      { hh = id / 40; const int r = id - hh * 40; nt = r & 7; mt = r >> 3; }
  else if (MODE == 0) { mt = id & 7;  nt = id >> 3; }   // 8 ids sharing one B-tile adjacent
  else                { nt = id & 7;  mt = id >> 3; }   // 8 ids sharing one A-tile adjacent
  const int m0 = mt * 128, n0 = nt * 128;

  const unsigned short* Abase = (MODE == 1) ? A + (size_t)hh * 640 * 608 : A;
  const unsigned short* gA0 = Abase + (size_t)(m0 + w * 32 + lr) * lda + lc;
  const unsigned short* gA1 = gA0 + (size_t)16 * lda;
  const unsigned short* gB0;
  const unsigned short* gB1;
  if (MODE == 1) {
    // B row n -> VT[hh*64 + (n&63)] at column offset (n>>6)*584
    const int nb0 = n0 + w * 32 + lr;
    const int nb1 = nb0 + 16;
    gB0 = B + (size_t)(hh * 64 + (nb0 & 63)) * 9344 + (nb0 >> 6) * 584 + lc;
    gB1 = B + (size_t)(hh * 64 + (nb1 & 63)) * 9344 + (nb1 >> 6) * 584 + lc;
  } else {
    gB0 = B + (size_t)(n0 + w * 32 + lr) * ldb + lc;
    gB1 = gB0 + (size_t)16 * ldb;
  }

  f32x4 acc[4][4] = {};
  const int NT = K >> 5;

#define STAGE(AS, BS, k0)                         \
  do {                                            \
    gl_lds16(gA0 + (k0), (AS) + w * 1024);        \
    gl_lds16(gA1 + (k0), (AS) + w * 1024 + 512);  \
    gl_lds16(gB0 + (k0), (BS) + w * 1024);        \
    gl_lds16(gB1 + (k0), (BS) + w * 1024 + 512);  \
  } while (0)

#define COMPUTE(AS, BS)                                                        \
  do {                                                                         \
    u32x4 af[4], bv[4];                                                        \
    _Pragma("unroll")                                                          \
    for (int i = 0; i < 4; i++)                                                \
      af[i] = *(const u32x4*)&(AS)[(wm * 64 + i * 16 + l15) * 32 + (lhi << 3)];\
    _Pragma("unroll")                                                          \
    for (int i = 0; i < 4; i++)                                                \
      bv[i] = *(const u32x4*)&(BS)[(wn * 64 + i * 16 + l15) * 32 + (lhi << 3)];\
    _Pragma("unroll")                                                          \
    for (int i = 0; i < 4; i++)                                                \
      _Pragma("unroll")                                                        \
      for (int j = 0; j < 4; j++)                                              \
        mfma16(acc[i][j], af[i], bv[j]);                                       \
  } while (0)

  STAGE(As0, Bs0, 0);
  __syncthreads();                       // buf0 ready
  for (int kt = 0; kt < NT; kt += 2) {
    if (kt + 1 < NT) STAGE(As1, Bs1, (kt + 1) << 5);   // issue next before compute
    COMPUTE(As0, Bs0);
    __syncthreads();                     // buf1 ready; everyone done with buf0
    if (kt + 1 < NT) {
      if (kt + 2 < NT) STAGE(As0, Bs0, (kt + 2) << 5);
      COMPUTE(As1, Bs1);
      __syncthreads();
    }
  }
#undef STAGE
#undef COMPUTE

  const int rb = m0 + wm * 64 + (lhi << 2);
  const int cb = n0 + wn * 64 + l15;
  #pragma unroll
  for (int i = 0; i < 4; i++) {
    #pragma unroll
    for (int r = 0; r < 4; r++) {
      const int row = rb + i * 16 + r;
      if (MODE == 0) {
        const float rbias = bias[row];
        #pragma unroll
        for (int j = 0; j < 4; j++) {
          const int col = cb + j * 16;
          ((unsigned short*)Cv)[(size_t)row * ldc + col] = f2h(acc[i][j][r] + rbias);
        }
      } else if (MODE == 1) {
        if (row < 577) {
          #pragma unroll
          for (int j = 0; j < 4; j++) {
            const int n = cb + j * 16;
            const int b = n >> 6, d = n & 63;
            ((unsigned short*)Cv)[(((size_t)b * 577 + row) << 10) + hh * 64 + d] =
                f2h(acc[i][j][r]);
          }
        }
      } else {
        if (row < 9232) {
          #pragma unroll
          for (int j = 0; j < 4; j++) {
            const int col = cb + j * 16;
            ((float*)Cv)[(size_t)row * ldc + col] = acc[i][j][r] + bias[col];
          }
        }
      }
    }
  }
}

extern "C" void kernel_launch(void* const* d_in, const int* in_sizes, int n_in,
                              void* d_out, int out_size, void* d_ws, size_t ws_size,
                              hipStream_t stream) {
  (void)in_sizes; (void)n_in; (void)out_size; (void)ws_size;
  const float* hs    = (const float*)d_in[0];
  const float* v_w   = (const float*)d_in[3];
  const float* v_b   = (const float*)d_in[4];
  const float* out_w = (const float*)d_in[5];
  const float* out_b = (const float*)d_in[6];
  const float* sb    = (const float*)d_in[8];
  float* out = (float*)d_out;

  char* ws = (char*)d_ws;
  constexpr size_t HS_SZ = (size_t)9344 * 1024 * 2;        // f16 hs; later reused as out_h
  constexpr size_t W_SZ  = (size_t)1024 * 1024 * 2;
  constexpr size_t VT_SZ = (size_t)1024 * 9344 * 2 + 256;  // + slack for b=15 K-tail reads
  unsigned short* hs_f16 = (unsigned short*)(ws);
  unsigned short* vw_f16 = (unsigned short*)(ws + HS_SZ);
  unsigned short* ow_f16 = (unsigned short*)(ws + HS_SZ + W_SZ);
  unsigned short* vt     = (unsigned short*)(ws + HS_SZ + 2 * W_SZ);
  unsigned short* pmat   = (unsigned short*)(ws + HS_SZ + 2 * W_SZ + VT_SZ);

  prep_hs_kernel<<<9344, 256, 0, stream>>>(hs, hs_f16);
  prep_w_kernel<<<1024, 256, 0, stream>>>(v_w, vw_f16);
  prep_w_kernel<<<1024, 256, 0, stream>>>(out_w, ow_f16);
  softmax_kernel<<<dim3(640, 16), 256, 0, stream>>>(sb, pmat);
  // GEMM1: VT[e][nn] = vw[e,:]·hs[nn,:] + v_b[e]; M=1024, N=9344, K=1024 (584 blocks)
  gemm_db_kernel<0><<<584, 256, 0, stream>>>(vw_f16, 1024, hs_f16, 1024, v_b,
                                             (void*)vt, 9344, 1024);
  // PV per head: M=640(P rows), N=1024(=(b,d)), K=608 (640 blocks); out_h -> hs_f16 buffer
  gemm_db_kernel<1><<<640, 256, 0, stream>>>(pmat, 608, vt, 0, nullptr,
                                             (void*)hs_f16, 0, 608);
  // GEMM4: out[m][e] = out_h[m,:]·ow[e,:] + out_b[e]; M=9344(store<9232), N=1024 (584 blocks)
  gemm_db_kernel<2><<<584, 256, 0, stream>>>(hs_f16, 1024, ow_f16, 1024, out_b,
                                             (void*)out, 1024, 1024);
}